// Round 17
// baseline (87.215 us; speedup 1.0000x reference)
//
#include <hip/hip_runtime.h>
#include <hip/hip_bf16.h>

#define NNODES 4096
#define NEDGES 131072
#define D_IN   768
#define D_H    256
#define NHEAD  4
#define D_HEAD 64
#define D_OUT  128
#define DEGCAP 192
#define S_SCALE 1048576.0f          // 2^20 fixed-point for deterministic S atomics
#define S_STRIDE 16                 // one u64 counter per 128B line (decontend atomics)

typedef __attribute__((ext_vector_type(4))) float f32x4;
typedef __attribute__((ext_vector_type(8))) short bf16x8;
typedef __attribute__((ext_vector_type(8))) unsigned short u16x8;

static __device__ __forceinline__ unsigned short f2bf(float f) {
    __hip_bfloat16 h = __float2bfloat16(f);
    return *reinterpret_cast<unsigned short*>(&h);
}
static __device__ __forceinline__ float bf2f(unsigned short u) {
    return __uint_as_float((unsigned)u << 16);
}

// ---------------- workspace layout (bytes) ----------------
#define OFF_XB     (0u)                          // 4096*768*2 = 6MB (x as bf16)
#define OFF_H0     (6u<<20)                      // 2MB bf16
#define OFF_H1     (8u<<20)                      // 2MB bf16
#define OFF_HH     (10u<<20)                     // 2MB bf16
#define OFF_SINT   (12u<<20)                     // 2 layers * 256 * 16 * 8B = 64KB
#define OFF_SSRC   (OFF_SINT + 65536u)           // 65536
#define OFF_SDST   (OFF_SSRC + 65536u)           // 65536
#define OFF_WINT   (OFF_SDST + 65536u)           // 393216
#define OFF_WGT    (OFF_WINT + 393216u)          // 262144
#define OFF_WOUTT  (OFF_WGT + 262144u)           // 65536
#define OFF_BM     (OFF_WOUTT + 65536u)          // 2MB

// ---------------- init: zero bitmap + Sint + weight convert + x -> bf16 ----------------
__global__ __launch_bounds__(256) void k_init(
    const float* __restrict__ Win, const float* __restrict__ Wg,
    const float* __restrict__ Wout, const float* __restrict__ x,
    unsigned short* __restrict__ WinT, unsigned short* __restrict__ WgT,
    unsigned short* __restrict__ WoutT, unsigned short* __restrict__ xb,
    uint4* __restrict__ bm4, unsigned long long* __restrict__ Sint)
{
    __shared__ float tile[32][33];
    const int tid = threadIdx.x, bid = blockIdx.x;
    bm4[bid*256 + tid] = make_uint4(0u,0u,0u,0u);
    if (bid < 32) Sint[bid*256 + tid] = 0ull;     // 2*256*16 = 8192 u64

    // x -> bf16 (identical rounding to in-staging convert)
    {
        const float4* x4 = (const float4*)x;
        ushort4* xb4 = (ushort4*)xb;
        for (int i = bid*256 + tid; i < (NNODES*D_IN)/4; i += 512*256) {
            float4 v = x4[i];
            ushort4 o;
            o.x = f2bf(v.x); o.y = f2bf(v.y); o.z = f2bf(v.z); o.w = f2bf(v.w);
            xb4[i] = o;
        }
    }

    if (bid < 352) {
        const float* src; unsigned short* dst; int R, Cc, tr, tc;
        if (bid < 192)      { src = Win;  dst = WinT;  R = 768; Cc = 256; tr = bid >> 3; tc = bid & 7; }
        else if (bid < 320) { int t = bid - 192; int m = t >> 4, s = t & 15;
                              src = Wg + (size_t)m*16384; dst = WgT + (size_t)m*16384;
                              R = 256; Cc = 64; tr = s >> 1; tc = s & 1; }
        else                { int t = bid - 320; src = Wout; dst = WoutT;
                              R = 256; Cc = 128; tr = t >> 2; tc = t & 3; }
        int ci = tid & 31, rq = tid >> 5;
        #pragma unroll
        for (int rr = rq; rr < 32; rr += 8)
            tile[rr][ci] = src[(size_t)(tr*32+rr)*Cc + tc*32 + ci];
        __syncthreads();
        int ri = tid & 31, cq = tid >> 5;
        #pragma unroll
        for (int cc = cq; cc < 32; cc += 8)
            dst[(size_t)(tc*32+cc)*R + tr*32 + ri] = f2bf(tile[ri][cc]);
    }
}

// ---------------- MFMA GEMM: C = act(A@B + bias), A/B both bf16 ----------------
// A: MxK bf16 row-major. BT: NxK bf16 (pre-transposed). 32x64 tile, BK=64,
// 256 thr = 4 waves (wave = 16-col strip), 4 MFMA/wave/iter.
// ei != null (h0): 1D grid of 512, XCD-swizzled bx/by + edge-bitmap tail.
// a_l != null (hh): epilogue computes ssrc/sdst + padded fixed-point Sint sums.
__global__ __launch_bounds__(256) void gemm_mfma(
    const unsigned short* __restrict__ A, const unsigned short* __restrict__ BT,
    const float* __restrict__ bias, float* __restrict__ Cf,
    unsigned short* __restrict__ Cb,
    int N, int K, int relu,
    const float* __restrict__ a_l, float* __restrict__ ssrc,
    float* __restrict__ sdst, unsigned long long* __restrict__ Sint,
    const int* __restrict__ ei, unsigned* __restrict__ bm)
{
    __shared__ unsigned short As[32][72];   // [row][k] bf16, 144B stride (2-way banks: free)
    __shared__ unsigned short Bs[64][72];   // [col][k] bf16
    __shared__ float sredS[4][32], sredD[4][32];
    const int tid = threadIdx.x;
    int bx, by;
    if (ei) {   // h0: 1D grid 512, nbx=4, XCD-aware remap (bijective)
        int bid = blockIdx.x;
        int xcd = bid & 7, q = bid >> 3;
        bx = q & 3;
        by = (q >> 2)*8 + xcd;
    } else {
        bx = blockIdx.x; by = blockIdx.y;
    }
    const int wc = tid >> 6;                 // wave id = column strip
    const int lane = tid & 63;
    const int g = lane >> 4, c = lane & 15;
    const int ar = tid >> 3, ak = (tid & 7) * 8;   // A stage: 32r x (8thr x 8 u16)
    const int bc = tid >> 2, bk = (tid & 3) * 16;  // B stage: 64c x (4thr x 16 u16)
    f32x4 acc0 = {0.f,0.f,0.f,0.f}, acc1 = {0.f,0.f,0.f,0.f};
    const unsigned short* Arow = A + (size_t)(by*32 + ar)*K;
    const unsigned short* Brow = BT + (size_t)(bx*64 + bc)*K;

    for (int k0 = 0; k0 < K; k0 += 64) {
        u16x8 avv = *(const u16x8*)&Arow[k0 + ak];
        u16x8 bv0 = *(const u16x8*)&Brow[k0 + bk];
        u16x8 bv1 = *(const u16x8*)&Brow[k0 + bk + 8];
        *(u16x8*)&As[ar][ak]     = avv;
        *(u16x8*)&Bs[bc][bk]     = bv0;
        *(u16x8*)&Bs[bc][bk + 8] = bv1;
        __syncthreads();
        bf16x8 b0  = *(bf16x8*)&Bs[wc*16 + c][g*8];
        bf16x8 b1  = *(bf16x8*)&Bs[wc*16 + c][32 + g*8];
        bf16x8 a00 = *(bf16x8*)&As[c][g*8];
        bf16x8 a01 = *(bf16x8*)&As[c][32 + g*8];
        bf16x8 a10 = *(bf16x8*)&As[16 + c][g*8];
        bf16x8 a11 = *(bf16x8*)&As[16 + c][32 + g*8];
        acc0 = __builtin_amdgcn_mfma_f32_16x16x32_bf16(a00, b0, acc0, 0, 0, 0);
        acc0 = __builtin_amdgcn_mfma_f32_16x16x32_bf16(a01, b1, acc0, 0, 0, 0);
        acc1 = __builtin_amdgcn_mfma_f32_16x16x32_bf16(a10, b0, acc1, 0, 0, 0);
        acc1 = __builtin_amdgcn_mfma_f32_16x16x32_bf16(a11, b1, acc1, 0, 0, 0);
        __syncthreads();
    }

    const int col = bx*64 + wc*16 + c;
    float bb = bias ? bias[col] : 0.f;
    #pragma unroll
    for (int t = 0; t < 2; ++t) {
        f32x4 av = t ? acc1 : acc0;
        #pragma unroll
        for (int i = 0; i < 4; ++i) {
            int r = by*32 + t*16 + g*4 + i;
            float v = av[i] + bb;
            if (relu) v = fmaxf(v, 0.f);
            if (Cb) Cb[(size_t)r*N + col] = f2bf(v);
            else    Cf[(size_t)r*N + col] = v;
        }
    }

    if (a_l) {
        int h = bx;
        float as = a_l[h*128 + wc*16 + c];
        float ad = a_l[h*128 + 64 + wc*16 + c];
        float ps[8], pd[8], cs = 0.f;
        #pragma unroll
        for (int t = 0; t < 2; ++t) {
            f32x4 av = t ? acc1 : acc0;
            #pragma unroll
            for (int i = 0; i < 4; ++i) {
                ps[t*4+i] = av[i] * as;
                pd[t*4+i] = av[i] * ad;
                cs += av[i];
            }
        }
        #pragma unroll
        for (int off = 1; off < 16; off <<= 1) {
            #pragma unroll
            for (int j = 0; j < 8; ++j) {
                ps[j] += __shfl_xor(ps[j], off);
                pd[j] += __shfl_xor(pd[j], off);
            }
        }
        if (c == 0) {
            #pragma unroll
            for (int t = 0; t < 2; ++t)
                #pragma unroll
                for (int i = 0; i < 4; ++i) {
                    sredS[wc][t*16 + g*4 + i] = ps[t*4+i];
                    sredD[wc][t*16 + g*4 + i] = pd[t*4+i];
                }
        }
        // 32-row column sum -> deterministic fixed-point atomic (padded lines)
        cs += __shfl_xor(cs, 16);
        cs += __shfl_xor(cs, 32);
        if (g == 0) {
            long long q = (long long)llrintf(cs * S_SCALE);
            atomicAdd(&Sint[(size_t)col * S_STRIDE], (unsigned long long)q);
        }
        __syncthreads();
        if (tid < 32) {
            float s1 = sredS[0][tid] + sredS[1][tid] + sredS[2][tid] + sredS[3][tid];
            float s2 = sredD[0][tid] + sredD[1][tid] + sredD[2][tid] + sredD[3][tid];
            int r = by*32 + tid;
            ssrc[r*4 + h] = s1;
            sdst[r*4 + h] = s2;
        }
    }

    if (ei) {
        // adjacency bitmap build: 512 blocks x 256 threads == NEDGES (flat bid)
        __shared__ int flag;
        int bid = blockIdx.x;
        if (tid < 64) {
            int v = ei[2*tid + 1];
            unsigned long long ball = __ballot(v == 0);
            if (tid == 0) flag = (ball == ~0ull) ? 1 : 0;
        }
        __syncthreads();
        int is64 = flag;
        int k = bid*256 + tid;
        int r  = is64 ? ei[2*k]            : ei[k];
        int cc = is64 ? ei[2*NEDGES + 2*k] : ei[NEDGES + k];
        r &= (NNODES-1); cc &= (NNODES-1);
        atomicOr(&bm[(size_t)r*128 + (cc>>5)], 1u << (cc & 31));
    }
}

// ---------------- per-node aggregation + dense-softmax + relu (bf16 out) ----------------
// 1024 blocks x 4 nodes grid-stride. Per-WAVE private csr/w LDS slices: waves
// are fully independent (wave h = head h of the block's current node), no
// barriers anywhere, nodes pipeline per wave. Exact dense-softmax identity:
//   M = max(0, max_e e); base = exp(-M)
//   Z = sum_edges(exp(e-M)-base) + N*base
//   hp = [ sum_edges (exp(e-M)-base)*hh[m] + base*S ] / Z
__global__ __launch_bounds__(256) void aggregate_kernel(
    const unsigned* __restrict__ bm,
    const float* __restrict__ ssrc, const float* __restrict__ sdst,
    const unsigned short* __restrict__ hh,
    const unsigned long long* __restrict__ Sint,
    unsigned short* __restrict__ hout)
{
    __shared__ int   csr_lds[4][DEGCAP];
    __shared__ float w_lds[4][DEGCAP];
    const int tid = threadIdx.x;
    const int h = tid >> 6, o = tid & 63;       // o == lane
    int* csr = csr_lds[h];
    float* wl = w_lds[h];
    const float Sv = (float)(long long)Sint[(size_t)(h*64 + o) * S_STRIDE]
                     * (1.0f / S_SCALE);

    for (int v = 0; v < 4; ++v) {
        const int n = v*1024 + blockIdx.x;
        const unsigned* brow = bm + (size_t)n*128;

        // per-wave list build into this wave's private slice
        unsigned wA = brow[2*o], wB = brow[2*o + 1];
        int cpc = __popc(wA) + __popc(wB);
        int pre = cpc;
        #pragma unroll
        for (int off = 1; off < 64; off <<= 1) {
            int t = __shfl_up(pre, off);
            if (o >= off) pre += t;
        }
        int excl = pre - cpc;
        int cnt = __shfl(pre, 63);
        if (cnt <= DEGCAP) {
            int pos = excl, base = o*64;
            unsigned w = wA;
            while (w) { int b = __builtin_ctz(w); csr[pos++] = base + b; w &= w-1; }
            w = wB; base += 32;
            while (w) { int b = __builtin_ctz(w); csr[pos++] = base + b; w &= w-1; }
        }
        float ss = ssrc[n*4 + h];

        if (cnt <= DEGCAP) {
            // pass A: single sdst gather; stage e, track max (baseline 0 non-edges)
            float mx = 0.f;
            for (int i = o; i < cnt; i += 64) {
                int m = csr[i];
                float e = ss + sdst[m*4 + h];
                e = (e >= 0.f) ? e : 0.2f*e;
                wl[i] = e;
                mx = fmaxf(mx, e);
            }
            #pragma unroll
            for (int off = 32; off; off >>= 1) mx = fmaxf(mx, __shfl_xor(mx, off));
            float M = mx;
            float base = expf(-M);

            // pass B: exponentiate in place (LDS-only)
            float zp = 0.f;
            for (int i = o; i < cnt; i += 64) {
                float w = expf(wl[i] - M) - base;
                wl[i] = w;
                zp += w;
            }
            #pragma unroll
            for (int off = 32; off; off >>= 1) zp += __shfl_xor(zp, off);

            // accumulate: 8 independent gathers in flight (same sequential FP order)
            float acc = 0.f;
            int i = 0;
            for (; i + 8 <= cnt; i += 8) {
                int   mm[8]; float wq[8]; float vq[8];
                #pragma unroll
                for (int j = 0; j < 8; ++j) {
                    mm[j] = csr[i+j];
                    wq[j] = wl[i+j];
                }
                #pragma unroll
                for (int j = 0; j < 8; ++j)
                    vq[j] = bf2f(hh[(size_t)mm[j]*256 + h*64 + o]);
                #pragma unroll
                for (int j = 0; j < 8; ++j)
                    acc += wq[j] * vq[j];
            }
            for (; i < cnt; ++i)
                acc += wl[i] * bf2f(hh[(size_t)csr[i]*256 + h*64 + o]);

            float Z  = zp + (float)NNODES * base;
            float hp = (acc + base * Sv) / Z;
            hout[(size_t)n*256 + h*64 + o] = f2bf(fmaxf(hp, 0.f));
        } else {
            // overflow fallback (never expected for Poisson(32) rows): direct scan
            float mx = 0.f;
            for (int m = o; m < NNODES; m += 64) {
                if ((brow[m>>5] >> (m & 31)) & 1u) {
                    float e = ss + sdst[m*4 + h];
                    e = (e >= 0.f) ? e : 0.2f*e;
                    mx = fmaxf(mx, e);
                }
            }
            #pragma unroll
            for (int off = 32; off; off >>= 1) mx = fmaxf(mx, __shfl_xor(mx, off));
            float M = mx;
            float base = expf(-M);
            float zp = 0.f, acc = 0.f;
            for (int m = 0; m < NNODES; ++m) {
                if ((brow[m>>5] >> (m & 31)) & 1u) {
                    float e = ss + sdst[m*4 + h];
                    e = (e >= 0.f) ? e : 0.2f*e;
                    float w = expf(e - M) - base;
                    zp += w;
                    acc += w * bf2f(hh[(size_t)m*256 + h*64 + o]);
                }
            }
            float Z  = zp + (float)NNODES * base;
            float hp = (acc + base * Sv) / Z;
            hout[(size_t)n*256 + h*64 + o] = f2bf(fmaxf(hp, 0.f));
        }
    }
}

// ---------------- host: size-based input resolution ----------------
static int find_size(const int* sz, int n, int want, int fallback)
{
    for (int i = 0; i < n; ++i) if (sz[i] == want) return i;
    return fallback;
}

extern "C" void kernel_launch(void* const* d_in, const int* in_sizes, int n_in,
                              void* d_out, int out_size, void* d_ws, size_t ws_size,
                              hipStream_t stream)
{
    int ix   = find_size(in_sizes, n_in, NNODES*D_IN, 0);
    int ie   = find_size(in_sizes, n_in, 2*NEDGES, 1);
    int iwin = find_size(in_sizes, n_in, D_IN*D_H, 2);
    int ibin = find_size(in_sizes, n_in, D_H, 3);
    int iwg  = find_size(in_sizes, n_in, 2*NHEAD*D_H*D_HEAD, 4);
    int ia   = find_size(in_sizes, n_in, 2*NHEAD*2*D_HEAD, 5);
    int iwo  = find_size(in_sizes, n_in, D_H*D_OUT, 6);
    int ibo  = find_size(in_sizes, n_in, D_OUT, 7);

    const float* x    = (const float*)d_in[ix];
    const int*   ei   = (const int*)d_in[ie];
    const float* Win  = (const float*)d_in[iwin];
    const float* bin_ = (const float*)d_in[ibin];
    const float* Wg   = (const float*)d_in[iwg];
    const float* a    = (const float*)d_in[ia];
    const float* Wout = (const float*)d_in[iwo];
    const float* bout = (const float*)d_in[ibo];
    float* out = (float*)d_out;

    char* ws = (char*)d_ws;
    unsigned short*     xb    = (unsigned short*)(ws + OFF_XB);
    unsigned short*     h0    = (unsigned short*)(ws + OFF_H0);
    unsigned short*     h1    = (unsigned short*)(ws + OFF_H1);
    unsigned short*     hh    = (unsigned short*)(ws + OFF_HH);
    unsigned long long* Sint  = (unsigned long long*)(ws + OFF_SINT);
    float*              ssrc  = (float*)(ws + OFF_SSRC);
    float*              sdst  = (float*)(ws + OFF_SDST);
    unsigned short*     WinT  = (unsigned short*)(ws + OFF_WINT);
    unsigned short*     WgT   = (unsigned short*)(ws + OFF_WGT);
    unsigned short*     WoutT = (unsigned short*)(ws + OFF_WOUTT);
    unsigned*           bm    = (unsigned*)(ws + OFF_BM);

    // d1: zero bitmap + Sint + weight convert + x->bf16 (disjoint memory)
    k_init<<<512, 256, 0, stream>>>(Win, Wg, Wout, x, WinT, WgT, WoutT, xb,
                                    (uint4*)bm, Sint);

    // d2: h0 = relu(xb @ Win + bin) (bf16 out, XCD-swizzled) + edge bitmap tail
    gemm_mfma<<<512, 256, 0, stream>>>(xb, WinT, bin_, nullptr, h0,
                                       D_H, D_IN, 1,
                                       nullptr, nullptr, nullptr, nullptr,
                                       ei, bm);

    unsigned short* hin = h0;
    unsigned short* hcur = h1;
    for (int l = 0; l < 2; ++l) {
        // d3/d5: hh = hin @ Wg[l] (bf16 out, + scores + padded fixed-point S atomics)
        dim3 g2(D_H/64, NNODES/32);
        gemm_mfma<<<g2, 256, 0, stream>>>(hin, WgT + (size_t)l*NHEAD*D_HEAD*D_H,
                                          nullptr, nullptr, hh,
                                          D_H, D_H, 0,
                                          a + (size_t)l*NHEAD*128, ssrc, sdst,
                                          Sint + (size_t)l*256*S_STRIDE,
                                          nullptr, nullptr);
        // d4/d6: aggregate (bf16 out, 1024x4 grid-stride, per-wave LDS slices)
        aggregate_kernel<<<1024, 256, 0, stream>>>(bm, ssrc, sdst, hh,
                                                   Sint + (size_t)l*256*S_STRIDE,
                                                   hcur);
        unsigned short* t = hin; hin = hcur; hcur = t;
    }

    // d7: out = hin @ Wout + bout  (f32 out)
    {
        dim3 g(D_OUT/64, NNODES/32);
        gemm_mfma<<<g, 256, 0, stream>>>(hin, WoutT, bout, out, nullptr,
                                         D_OUT, D_H, 0,
                                         nullptr, nullptr, nullptr, nullptr,
                                         nullptr, nullptr);
    }
}

// Round 18
// 79.710 us; speedup vs baseline: 1.0942x; 1.0942x over previous
//
#include <hip/hip_runtime.h>
#include <hip/hip_bf16.h>

#define NNODES 4096
#define NEDGES 131072
#define D_IN   768
#define D_H    256
#define NHEAD  4
#define D_HEAD 64
#define D_OUT  128
#define DEGCAP 192
#define S_SCALE 1048576.0f          // 2^20 fixed-point for deterministic S atomics

typedef __attribute__((ext_vector_type(4))) float f32x4;
typedef __attribute__((ext_vector_type(8))) short bf16x8;
typedef __attribute__((ext_vector_type(8))) unsigned short u16x8;

static __device__ __forceinline__ unsigned short f2bf(float f) {
    __hip_bfloat16 h = __float2bfloat16(f);
    return *reinterpret_cast<unsigned short*>(&h);
}
static __device__ __forceinline__ float bf2f(unsigned short u) {
    return __uint_as_float((unsigned)u << 16);
}

// ---------------- workspace layout (bytes) ----------------
#define OFF_XB     (0u)                          // 4096*768*2 = 6MB (x as bf16)
#define OFF_H0     (6u<<20)                      // 2MB bf16
#define OFF_H1     (8u<<20)                      // 2MB bf16
#define OFF_HH     (10u<<20)                     // 2MB bf16
#define OFF_SINT   (12u<<20)                     // 2 layers * 256 * 8B = 4096
#define OFF_SSRC   (OFF_SINT + 4096u)            // 65536
#define OFF_SDST   (OFF_SSRC + 65536u)           // 65536
#define OFF_WINT   (OFF_SDST + 65536u)           // 393216
#define OFF_WGT    (OFF_WINT + 393216u)          // 262144
#define OFF_WOUTT  (OFF_WGT + 262144u)           // 65536
#define OFF_BM     (OFF_WOUTT + 65536u)          // 2MB

// ---------------- init: zero bitmap + Sint + weight convert + x -> bf16 ----------------
__global__ __launch_bounds__(256) void k_init(
    const float* __restrict__ Win, const float* __restrict__ Wg,
    const float* __restrict__ Wout, const float* __restrict__ x,
    unsigned short* __restrict__ WinT, unsigned short* __restrict__ WgT,
    unsigned short* __restrict__ WoutT, unsigned short* __restrict__ xb,
    uint4* __restrict__ bm4, unsigned long long* __restrict__ Sint)
{
    __shared__ float tile[32][33];
    const int tid = threadIdx.x, bid = blockIdx.x;
    bm4[bid*256 + tid] = make_uint4(0u,0u,0u,0u);
    if (bid == 0) { Sint[tid] = 0ull; Sint[256 + tid] = 0ull; }

    // x -> bf16 (identical rounding to in-staging convert)
    {
        const float4* x4 = (const float4*)x;
        ushort4* xb4 = (ushort4*)xb;
        for (int i = bid*256 + tid; i < (NNODES*D_IN)/4; i += 512*256) {
            float4 v = x4[i];
            ushort4 o;
            o.x = f2bf(v.x); o.y = f2bf(v.y); o.z = f2bf(v.z); o.w = f2bf(v.w);
            xb4[i] = o;
        }
    }

    if (bid < 352) {
        const float* src; unsigned short* dst; int R, Cc, tr, tc;
        if (bid < 192)      { src = Win;  dst = WinT;  R = 768; Cc = 256; tr = bid >> 3; tc = bid & 7; }
        else if (bid < 320) { int t = bid - 192; int m = t >> 4, s = t & 15;
                              src = Wg + (size_t)m*16384; dst = WgT + (size_t)m*16384;
                              R = 256; Cc = 64; tr = s >> 1; tc = s & 1; }
        else                { int t = bid - 320; src = Wout; dst = WoutT;
                              R = 256; Cc = 128; tr = t >> 2; tc = t & 3; }
        int ci = tid & 31, rq = tid >> 5;
        #pragma unroll
        for (int rr = rq; rr < 32; rr += 8)
            tile[rr][ci] = src[(size_t)(tr*32+rr)*Cc + tc*32 + ci];
        __syncthreads();
        int ri = tid & 31, cq = tid >> 5;
        #pragma unroll
        for (int cc = cq; cc < 32; cc += 8)
            dst[(size_t)(tc*32+cc)*R + tr*32 + ri] = f2bf(tile[ri][cc]);
    }
}

// ---------------- MFMA GEMM: C = act(A@B + bias), A/B both bf16 ----------------
// A: MxK bf16 row-major. BT: NxK bf16 (pre-transposed). 32x64 tile, BK=64,
// 256 thr = 4 waves (wave = 16-col strip), 4 MFMA/wave/iter.
// ei != null (h0): 1D grid of 512, XCD-swizzled bx/by (same-by blocks -> same
//   XCD L2 for A-panel reuse) + adjacency-bitmap build appended in the tail.
// a_l != null (hh): epilogue computes ssrc/sdst + fixed-point Sint col sums.
__global__ __launch_bounds__(256) void gemm_mfma(
    const unsigned short* __restrict__ A, const unsigned short* __restrict__ BT,
    const float* __restrict__ bias, float* __restrict__ Cf,
    unsigned short* __restrict__ Cb,
    int N, int K, int relu,
    const float* __restrict__ a_l, float* __restrict__ ssrc,
    float* __restrict__ sdst, unsigned long long* __restrict__ Sint,
    const int* __restrict__ ei, unsigned* __restrict__ bm)
{
    __shared__ unsigned short As[32][72];   // [row][k] bf16, 144B stride (2-way banks: free)
    __shared__ unsigned short Bs[64][72];   // [col][k] bf16
    __shared__ float sredS[4][32], sredD[4][32];
    const int tid = threadIdx.x;
    int bx, by;
    if (ei) {   // h0: 1D grid 512, nbx=4, XCD-aware remap (bijective)
        int bid = blockIdx.x;
        int xcd = bid & 7, q = bid >> 3;
        bx = q & 3;
        by = (q >> 2)*8 + xcd;
    } else {
        bx = blockIdx.x; by = blockIdx.y;
    }
    const int wc = tid >> 6;                 // wave id = column strip
    const int lane = tid & 63;
    const int g = lane >> 4, c = lane & 15;
    const int ar = tid >> 3, ak = (tid & 7) * 8;   // A stage: 32r x (8thr x 8 u16)
    const int bc = tid >> 2, bk = (tid & 3) * 16;  // B stage: 64c x (4thr x 16 u16)
    f32x4 acc0 = {0.f,0.f,0.f,0.f}, acc1 = {0.f,0.f,0.f,0.f};
    const unsigned short* Arow = A + (size_t)(by*32 + ar)*K;
    const unsigned short* Brow = BT + (size_t)(bx*64 + bc)*K;

    for (int k0 = 0; k0 < K; k0 += 64) {
        u16x8 avv = *(const u16x8*)&Arow[k0 + ak];
        u16x8 bv0 = *(const u16x8*)&Brow[k0 + bk];
        u16x8 bv1 = *(const u16x8*)&Brow[k0 + bk + 8];
        *(u16x8*)&As[ar][ak]     = avv;
        *(u16x8*)&Bs[bc][bk]     = bv0;
        *(u16x8*)&Bs[bc][bk + 8] = bv1;
        __syncthreads();
        bf16x8 b0  = *(bf16x8*)&Bs[wc*16 + c][g*8];
        bf16x8 b1  = *(bf16x8*)&Bs[wc*16 + c][32 + g*8];
        bf16x8 a00 = *(bf16x8*)&As[c][g*8];
        bf16x8 a01 = *(bf16x8*)&As[c][32 + g*8];
        bf16x8 a10 = *(bf16x8*)&As[16 + c][g*8];
        bf16x8 a11 = *(bf16x8*)&As[16 + c][32 + g*8];
        acc0 = __builtin_amdgcn_mfma_f32_16x16x32_bf16(a00, b0, acc0, 0, 0, 0);
        acc0 = __builtin_amdgcn_mfma_f32_16x16x32_bf16(a01, b1, acc0, 0, 0, 0);
        acc1 = __builtin_amdgcn_mfma_f32_16x16x32_bf16(a10, b0, acc1, 0, 0, 0);
        acc1 = __builtin_amdgcn_mfma_f32_16x16x32_bf16(a11, b1, acc1, 0, 0, 0);
        __syncthreads();
    }

    const int col = bx*64 + wc*16 + c;
    float bb = bias ? bias[col] : 0.f;
    #pragma unroll
    for (int t = 0; t < 2; ++t) {
        f32x4 av = t ? acc1 : acc0;
        #pragma unroll
        for (int i = 0; i < 4; ++i) {
            int r = by*32 + t*16 + g*4 + i;
            float v = av[i] + bb;
            if (relu) v = fmaxf(v, 0.f);
            if (Cb) Cb[(size_t)r*N + col] = f2bf(v);
            else    Cf[(size_t)r*N + col] = v;
        }
    }

    if (a_l) {
        int h = bx;
        float as = a_l[h*128 + wc*16 + c];
        float ad = a_l[h*128 + 64 + wc*16 + c];
        float ps[8], pd[8], cs = 0.f;
        #pragma unroll
        for (int t = 0; t < 2; ++t) {
            f32x4 av = t ? acc1 : acc0;
            #pragma unroll
            for (int i = 0; i < 4; ++i) {
                ps[t*4+i] = av[i] * as;
                pd[t*4+i] = av[i] * ad;
                cs += av[i];
            }
        }
        #pragma unroll
        for (int off = 1; off < 16; off <<= 1) {
            #pragma unroll
            for (int j = 0; j < 8; ++j) {
                ps[j] += __shfl_xor(ps[j], off);
                pd[j] += __shfl_xor(pd[j], off);
            }
        }
        if (c == 0) {
            #pragma unroll
            for (int t = 0; t < 2; ++t)
                #pragma unroll
                for (int i = 0; i < 4; ++i) {
                    sredS[wc][t*16 + g*4 + i] = ps[t*4+i];
                    sredD[wc][t*16 + g*4 + i] = pd[t*4+i];
                }
        }
        // 32-row column sum -> deterministic fixed-point atomic
        cs += __shfl_xor(cs, 16);
        cs += __shfl_xor(cs, 32);
        if (g == 0) {
            long long q = (long long)llrintf(cs * S_SCALE);
            atomicAdd(&Sint[col], (unsigned long long)q);   // 2's-complement add
        }
        __syncthreads();
        if (tid < 32) {
            float s1 = sredS[0][tid] + sredS[1][tid] + sredS[2][tid] + sredS[3][tid];
            float s2 = sredD[0][tid] + sredD[1][tid] + sredD[2][tid] + sredD[3][tid];
            int r = by*32 + tid;
            ssrc[r*4 + h] = s1;
            sdst[r*4 + h] = s2;
        }
    }

    if (ei) {
        // adjacency bitmap build: 512 blocks x 256 threads == NEDGES (flat bid)
        __shared__ int flag;
        int bid = blockIdx.x;
        if (tid < 64) {
            int v = ei[2*tid + 1];
            unsigned long long ball = __ballot(v == 0);
            if (tid == 0) flag = (ball == ~0ull) ? 1 : 0;
        }
        __syncthreads();
        int is64 = flag;
        int k = bid*256 + tid;
        int r  = is64 ? ei[2*k]            : ei[k];
        int cc = is64 ? ei[2*NEDGES + 2*k] : ei[NEDGES + k];
        r &= (NNODES-1); cc &= (NNODES-1);
        atomicOr(&bm[(size_t)r*128 + (cc>>5)], 1u << (cc & 31));
    }
}

// ---------------- per-node aggregation + dense-softmax + relu (bf16 out) ----------------
// 4096 blocks x 1 node. Per-wave redundant list build (same-value LDS race is
// benign; LDS ops are in-order within a wave) -> no block barrier, no idle waves.
// Single-gather softmax: pass A stages e in w_lds during the max pass;
// pass B exponentiates from LDS (identical FP values/order as two-gather).
// Exact dense-softmax identity:
//   M = max(0, max_e e); base = exp(-M)
//   Z = sum_edges(exp(e-M)-base) + N*base
//   hp = [ sum_edges (exp(e-M)-base)*hh[m] + base*S ] / Z
__global__ __launch_bounds__(256) void aggregate_kernel(
    const unsigned* __restrict__ bm,
    const float* __restrict__ ssrc, const float* __restrict__ sdst,
    const unsigned short* __restrict__ hh,
    const unsigned long long* __restrict__ Sint,
    unsigned short* __restrict__ hout)
{
    __shared__ int   csr_lds[DEGCAP];
    __shared__ float w_lds[4*DEGCAP];
    int n = blockIdx.x;
    int tid = threadIdx.x;
    int h = tid >> 6, o = tid & 63;       // o == lane
    const unsigned* brow = bm + (size_t)n*128;
    float Sv = (float)(long long)Sint[h*64 + o] * (1.0f / S_SCALE);

    // per-wave list build (all 4 waves write identical values)
    unsigned wA = brow[2*o], wB = brow[2*o + 1];
    int cpc = __popc(wA) + __popc(wB);
    int pre = cpc;
    #pragma unroll
    for (int off = 1; off < 64; off <<= 1) {
        int v = __shfl_up(pre, off);
        if (o >= off) pre += v;
    }
    int excl = pre - cpc;
    int cnt = __shfl(pre, 63);
    if (cnt <= DEGCAP) {
        int pos = excl, base = o*64;
        unsigned w = wA;
        while (w) { int b = __builtin_ctz(w); csr_lds[pos++] = base + b; w &= w-1; }
        w = wB; base += 32;
        while (w) { int b = __builtin_ctz(w); csr_lds[pos++] = base + b; w &= w-1; }
    }
    float ss = ssrc[n*4 + h];

    if (cnt <= DEGCAP) {
        // pass A: single sdst gather; stage e, track max (baseline 0 non-edges)
        float mx = 0.f;
        for (int i = o; i < cnt; i += 64) {
            int m = csr_lds[i];
            float e = ss + sdst[m*4 + h];
            e = (e >= 0.f) ? e : 0.2f*e;
            w_lds[h*DEGCAP + i] = e;
            mx = fmaxf(mx, e);
        }
        #pragma unroll
        for (int off = 32; off; off >>= 1) mx = fmaxf(mx, __shfl_xor(mx, off));
        float M = mx;
        float base = expf(-M);

        // pass B: exponentiate in place (LDS-only)
        float zp = 0.f;
        for (int i = o; i < cnt; i += 64) {
            float w = expf(w_lds[h*DEGCAP + i] - M) - base;
            w_lds[h*DEGCAP + i] = w;
            zp += w;
        }
        #pragma unroll
        for (int off = 32; off; off >>= 1) zp += __shfl_xor(zp, off);

        // accumulate: 8 independent gathers in flight (same sequential FP order)
        float acc = 0.f;
        int i = 0;
        for (; i + 8 <= cnt; i += 8) {
            int   mm[8]; float wq[8]; float vq[8];
            #pragma unroll
            for (int j = 0; j < 8; ++j) {
                mm[j] = csr_lds[i+j];
                wq[j] = w_lds[h*DEGCAP + i + j];
            }
            #pragma unroll
            for (int j = 0; j < 8; ++j)
                vq[j] = bf2f(hh[(size_t)mm[j]*256 + h*64 + o]);
            #pragma unroll
            for (int j = 0; j < 8; ++j)
                acc += wq[j] * vq[j];
        }
        for (; i < cnt; ++i)
            acc += w_lds[h*DEGCAP+i] * bf2f(hh[(size_t)csr_lds[i]*256 + h*64 + o]);

        float Z  = zp + (float)NNODES * base;
        float hp = (acc + base * Sv) / Z;
        hout[(size_t)n*256 + h*64 + o] = f2bf(fmaxf(hp, 0.f));
    } else {
        // overflow fallback (never expected for Poisson(32) rows): direct scan
        float mx = 0.f;
        for (int m = o; m < NNODES; m += 64) {
            if ((brow[m>>5] >> (m & 31)) & 1u) {
                float e = ss + sdst[m*4 + h];
                e = (e >= 0.f) ? e : 0.2f*e;
                mx = fmaxf(mx, e);
            }
        }
        #pragma unroll
        for (int off = 32; off; off >>= 1) mx = fmaxf(mx, __shfl_xor(mx, off));
        float M = mx;
        float base = expf(-M);
        float zp = 0.f, acc = 0.f;
        for (int m = 0; m < NNODES; ++m) {
            if ((brow[m>>5] >> (m & 31)) & 1u) {
                float e = ss + sdst[m*4 + h];
                e = (e >= 0.f) ? e : 0.2f*e;
                float w = expf(e - M) - base;
                zp += w;
                acc += w * bf2f(hh[(size_t)m*256 + h*64 + o]);
            }
        }
        float Z  = zp + (float)NNODES * base;
        float hp = (acc + base * Sv) / Z;
        hout[(size_t)n*256 + h*64 + o] = f2bf(fmaxf(hp, 0.f));
    }
}

// ---------------- host: size-based input resolution ----------------
static int find_size(const int* sz, int n, int want, int fallback)
{
    for (int i = 0; i < n; ++i) if (sz[i] == want) return i;
    return fallback;
}

extern "C" void kernel_launch(void* const* d_in, const int* in_sizes, int n_in,
                              void* d_out, int out_size, void* d_ws, size_t ws_size,
                              hipStream_t stream)
{
    int ix   = find_size(in_sizes, n_in, NNODES*D_IN, 0);
    int ie   = find_size(in_sizes, n_in, 2*NEDGES, 1);
    int iwin = find_size(in_sizes, n_in, D_IN*D_H, 2);
    int ibin = find_size(in_sizes, n_in, D_H, 3);
    int iwg  = find_size(in_sizes, n_in, 2*NHEAD*D_H*D_HEAD, 4);
    int ia   = find_size(in_sizes, n_in, 2*NHEAD*2*D_HEAD, 5);
    int iwo  = find_size(in_sizes, n_in, D_H*D_OUT, 6);
    int ibo  = find_size(in_sizes, n_in, D_OUT, 7);

    const float* x    = (const float*)d_in[ix];
    const int*   ei   = (const int*)d_in[ie];
    const float* Win  = (const float*)d_in[iwin];
    const float* bin_ = (const float*)d_in[ibin];
    const float* Wg   = (const float*)d_in[iwg];
    const float* a    = (const float*)d_in[ia];
    const float* Wout = (const float*)d_in[iwo];
    const float* bout = (const float*)d_in[ibo];
    float* out = (float*)d_out;

    char* ws = (char*)d_ws;
    unsigned short*     xb    = (unsigned short*)(ws + OFF_XB);
    unsigned short*     h0    = (unsigned short*)(ws + OFF_H0);
    unsigned short*     h1    = (unsigned short*)(ws + OFF_H1);
    unsigned short*     hh    = (unsigned short*)(ws + OFF_HH);
    unsigned long long* Sint  = (unsigned long long*)(ws + OFF_SINT);
    float*              ssrc  = (float*)(ws + OFF_SSRC);
    float*              sdst  = (float*)(ws + OFF_SDST);
    unsigned short*     WinT  = (unsigned short*)(ws + OFF_WINT);
    unsigned short*     WgT   = (unsigned short*)(ws + OFF_WGT);
    unsigned short*     WoutT = (unsigned short*)(ws + OFF_WOUTT);
    unsigned*           bm    = (unsigned*)(ws + OFF_BM);

    // d1: zero bitmap + Sint + weight convert + x->bf16 (disjoint memory)
    k_init<<<512, 256, 0, stream>>>(Win, Wg, Wout, x, WinT, WgT, WoutT, xb,
                                    (uint4*)bm, Sint);

    // d2: h0 = relu(xb @ Win + bin) (bf16 out, XCD-swizzled) + edge bitmap tail
    gemm_mfma<<<512, 256, 0, stream>>>(xb, WinT, bin_, nullptr, h0,
                                       D_H, D_IN, 1,
                                       nullptr, nullptr, nullptr, nullptr,
                                       ei, bm);

    unsigned short* hin = h0;
    unsigned short* hcur = h1;
    for (int l = 0; l < 2; ++l) {
        // d3/d5: hh = hin @ Wg[l] (bf16 out, + scores + fixed-point S atomics)
        dim3 g2(D_H/64, NNODES/32);
        gemm_mfma<<<g2, 256, 0, stream>>>(hin, WgT + (size_t)l*NHEAD*D_HEAD*D_H,
                                          nullptr, nullptr, hh,
                                          D_H, D_H, 0,
                                          a + (size_t)l*NHEAD*128, ssrc, sdst,
                                          Sint + (size_t)l*256,
                                          nullptr, nullptr);
        // d4/d6: aggregate (bf16 out, 4096x1, per-wave barrier-free)
        aggregate_kernel<<<NNODES, 256, 0, stream>>>(bm, ssrc, sdst, hh,
                                                     Sint + (size_t)l*256, hcur);
        unsigned short* t = hin; hin = hcur; hcur = t;
    }

    // d7: out = hin @ Wout + bout  (f32 out)
    {
        dim3 g(D_OUT/64, NNODES/32);
        gemm_mfma<<<g, 256, 0, stream>>>(hin, WoutT, bout, out, nullptr,
                                         D_OUT, D_H, 0,
                                         nullptr, nullptr, nullptr, nullptr,
                                         nullptr, nullptr);
    }
}

// Round 19
// 72.086 us; speedup vs baseline: 1.2099x; 1.1058x over previous
//
#include <hip/hip_runtime.h>
#include <hip/hip_bf16.h>

#define NNODES 4096
#define NEDGES 131072
#define D_IN   768
#define D_H    256
#define NHEAD  4
#define D_HEAD 64
#define D_OUT  128
#define DEGCAP 192
#define S_SCALE 1048576.0f          // 2^20 fixed-point for deterministic S atomics

typedef __attribute__((ext_vector_type(4))) float f32x4;
typedef __attribute__((ext_vector_type(8))) short bf16x8;
typedef __attribute__((ext_vector_type(8))) unsigned short u16x8;

static __device__ __forceinline__ unsigned short f2bf(float f) {
    __hip_bfloat16 h = __float2bfloat16(f);
    return *reinterpret_cast<unsigned short*>(&h);
}
static __device__ __forceinline__ float bf2f(unsigned short u) {
    return __uint_as_float((unsigned)u << 16);
}

// ---------------- workspace layout (bytes) ----------------
#define OFF_XB     (0u)                          // 4096*768*2 = 6MB (x as bf16)
#define OFF_H0     (6u<<20)                      // 2MB bf16
#define OFF_H1     (8u<<20)                      // 2MB bf16
#define OFF_HH     (10u<<20)                     // 2MB bf16
#define OFF_SINT   (12u<<20)                     // 2 layers * 256 * 8B = 4096
#define OFF_SSRC   (OFF_SINT + 4096u)            // 65536
#define OFF_SDST   (OFF_SSRC + 65536u)           // 65536
#define OFF_WINT   (OFF_SDST + 65536u)           // 393216
#define OFF_WGT    (OFF_WINT + 393216u)          // 262144
#define OFF_WOUTT  (OFF_WGT + 262144u)           // 65536
#define OFF_BM     (OFF_WOUTT + 65536u)          // 2MB

// ---------------- init: zero bitmap + Sint + weight convert + x -> bf16 ----------------
__global__ __launch_bounds__(256) void k_init(
    const float* __restrict__ Win, const float* __restrict__ Wg,
    const float* __restrict__ Wout, const float* __restrict__ x,
    unsigned short* __restrict__ WinT, unsigned short* __restrict__ WgT,
    unsigned short* __restrict__ WoutT, unsigned short* __restrict__ xb,
    uint4* __restrict__ bm4, unsigned long long* __restrict__ Sint)
{
    __shared__ float tile[32][33];
    const int tid = threadIdx.x, bid = blockIdx.x;
    bm4[bid*256 + tid] = make_uint4(0u,0u,0u,0u);
    if (bid == 0) { Sint[tid] = 0ull; Sint[256 + tid] = 0ull; }

    // x -> bf16 (identical rounding to in-staging convert)
    {
        const float4* x4 = (const float4*)x;
        ushort4* xb4 = (ushort4*)xb;
        for (int i = bid*256 + tid; i < (NNODES*D_IN)/4; i += 512*256) {
            float4 v = x4[i];
            ushort4 o;
            o.x = f2bf(v.x); o.y = f2bf(v.y); o.z = f2bf(v.z); o.w = f2bf(v.w);
            xb4[i] = o;
        }
    }

    if (bid < 352) {
        const float* src; unsigned short* dst; int R, Cc, tr, tc;
        if (bid < 192)      { src = Win;  dst = WinT;  R = 768; Cc = 256; tr = bid >> 3; tc = bid & 7; }
        else if (bid < 320) { int t = bid - 192; int m = t >> 4, s = t & 15;
                              src = Wg + (size_t)m*16384; dst = WgT + (size_t)m*16384;
                              R = 256; Cc = 64; tr = s >> 1; tc = s & 1; }
        else                { int t = bid - 320; src = Wout; dst = WoutT;
                              R = 256; Cc = 128; tr = t >> 2; tc = t & 3; }
        int ci = tid & 31, rq = tid >> 5;
        #pragma unroll
        for (int rr = rq; rr < 32; rr += 8)
            tile[rr][ci] = src[(size_t)(tr*32+rr)*Cc + tc*32 + ci];
        __syncthreads();
        int ri = tid & 31, cq = tid >> 5;
        #pragma unroll
        for (int cc = cq; cc < 32; cc += 8)
            dst[(size_t)(tc*32+cc)*R + tr*32 + ri] = f2bf(tile[ri][cc]);
    }
}

// ---------------- MFMA GEMM: C = act(A@B + bias), A/B both bf16 ----------------
// A: MxK bf16 row-major. BT: NxK bf16 (pre-transposed). 32x64 tile, BK=64,
// 256 thr = 4 waves (wave = 16-col strip), 4 MFMA/wave/iter.
// ei != null (h0): 1D grid of 512, XCD-swizzled bx/by + edge-bitmap tail.
// a_l != null (hh): epilogue computes ssrc/sdst + fixed-point Sint col sums.
__global__ __launch_bounds__(256) void gemm_mfma(
    const unsigned short* __restrict__ A, const unsigned short* __restrict__ BT,
    const float* __restrict__ bias, float* __restrict__ Cf,
    unsigned short* __restrict__ Cb,
    int N, int K, int relu,
    const float* __restrict__ a_l, float* __restrict__ ssrc,
    float* __restrict__ sdst, unsigned long long* __restrict__ Sint,
    const int* __restrict__ ei, unsigned* __restrict__ bm)
{
    __shared__ unsigned short As[32][72];   // [row][k] bf16, 144B stride (2-way banks: free)
    __shared__ unsigned short Bs[64][72];   // [col][k] bf16
    __shared__ float sredS[4][32], sredD[4][32];
    const int tid = threadIdx.x;
    int bx, by;
    if (ei) {   // h0: 1D grid 512, nbx=4, XCD-aware remap (bijective)
        int bid = blockIdx.x;
        int xcd = bid & 7, q = bid >> 3;
        bx = q & 3;
        by = (q >> 2)*8 + xcd;
    } else {
        bx = blockIdx.x; by = blockIdx.y;
    }
    const int wc = tid >> 6;                 // wave id = column strip
    const int lane = tid & 63;
    const int g = lane >> 4, c = lane & 15;
    const int ar = tid >> 3, ak = (tid & 7) * 8;   // A stage: 32r x (8thr x 8 u16)
    const int bc = tid >> 2, bk = (tid & 3) * 16;  // B stage: 64c x (4thr x 16 u16)
    f32x4 acc0 = {0.f,0.f,0.f,0.f}, acc1 = {0.f,0.f,0.f,0.f};
    const unsigned short* Arow = A + (size_t)(by*32 + ar)*K;
    const unsigned short* Brow = BT + (size_t)(bx*64 + bc)*K;

    for (int k0 = 0; k0 < K; k0 += 64) {
        u16x8 avv = *(const u16x8*)&Arow[k0 + ak];
        u16x8 bv0 = *(const u16x8*)&Brow[k0 + bk];
        u16x8 bv1 = *(const u16x8*)&Brow[k0 + bk + 8];
        *(u16x8*)&As[ar][ak]     = avv;
        *(u16x8*)&Bs[bc][bk]     = bv0;
        *(u16x8*)&Bs[bc][bk + 8] = bv1;
        __syncthreads();
        bf16x8 b0  = *(bf16x8*)&Bs[wc*16 + c][g*8];
        bf16x8 b1  = *(bf16x8*)&Bs[wc*16 + c][32 + g*8];
        bf16x8 a00 = *(bf16x8*)&As[c][g*8];
        bf16x8 a01 = *(bf16x8*)&As[c][32 + g*8];
        bf16x8 a10 = *(bf16x8*)&As[16 + c][g*8];
        bf16x8 a11 = *(bf16x8*)&As[16 + c][32 + g*8];
        acc0 = __builtin_amdgcn_mfma_f32_16x16x32_bf16(a00, b0, acc0, 0, 0, 0);
        acc0 = __builtin_amdgcn_mfma_f32_16x16x32_bf16(a01, b1, acc0, 0, 0, 0);
        acc1 = __builtin_amdgcn_mfma_f32_16x16x32_bf16(a10, b0, acc1, 0, 0, 0);
        acc1 = __builtin_amdgcn_mfma_f32_16x16x32_bf16(a11, b1, acc1, 0, 0, 0);
        __syncthreads();
    }

    const int col = bx*64 + wc*16 + c;
    float bb = bias ? bias[col] : 0.f;
    #pragma unroll
    for (int t = 0; t < 2; ++t) {
        f32x4 av = t ? acc1 : acc0;
        #pragma unroll
        for (int i = 0; i < 4; ++i) {
            int r = by*32 + t*16 + g*4 + i;
            float v = av[i] + bb;
            if (relu) v = fmaxf(v, 0.f);
            if (Cb) Cb[(size_t)r*N + col] = f2bf(v);
            else    Cf[(size_t)r*N + col] = v;
        }
    }

    if (a_l) {
        int h = bx;
        float as = a_l[h*128 + wc*16 + c];
        float ad = a_l[h*128 + 64 + wc*16 + c];
        float ps[8], pd[8], cs = 0.f;
        #pragma unroll
        for (int t = 0; t < 2; ++t) {
            f32x4 av = t ? acc1 : acc0;
            #pragma unroll
            for (int i = 0; i < 4; ++i) {
                ps[t*4+i] = av[i] * as;
                pd[t*4+i] = av[i] * ad;
                cs += av[i];
            }
        }
        #pragma unroll
        for (int off = 1; off < 16; off <<= 1) {
            #pragma unroll
            for (int j = 0; j < 8; ++j) {
                ps[j] += __shfl_xor(ps[j], off);
                pd[j] += __shfl_xor(pd[j], off);
            }
        }
        if (c == 0) {
            #pragma unroll
            for (int t = 0; t < 2; ++t)
                #pragma unroll
                for (int i = 0; i < 4; ++i) {
                    sredS[wc][t*16 + g*4 + i] = ps[t*4+i];
                    sredD[wc][t*16 + g*4 + i] = pd[t*4+i];
                }
        }
        // 32-row column sum -> deterministic fixed-point atomic
        cs += __shfl_xor(cs, 16);
        cs += __shfl_xor(cs, 32);
        if (g == 0) {
            long long q = (long long)llrintf(cs * S_SCALE);
            atomicAdd(&Sint[col], (unsigned long long)q);   // 2's-complement add
        }
        __syncthreads();
        if (tid < 32) {
            float s1 = sredS[0][tid] + sredS[1][tid] + sredS[2][tid] + sredS[3][tid];
            float s2 = sredD[0][tid] + sredD[1][tid] + sredD[2][tid] + sredD[3][tid];
            int r = by*32 + tid;
            ssrc[r*4 + h] = s1;
            sdst[r*4 + h] = s2;
        }
    }

    if (ei) {
        // adjacency bitmap build: 512 blocks x 256 threads == NEDGES (flat bid)
        __shared__ int flag;
        int bid = blockIdx.x;
        if (tid < 64) {
            int v = ei[2*tid + 1];
            unsigned long long ball = __ballot(v == 0);
            if (tid == 0) flag = (ball == ~0ull) ? 1 : 0;
        }
        __syncthreads();
        int is64 = flag;
        int k = bid*256 + tid;
        int r  = is64 ? ei[2*k]            : ei[k];
        int cc = is64 ? ei[2*NEDGES + 2*k] : ei[NEDGES + k];
        r &= (NNODES-1); cc &= (NNODES-1);
        atomicOr(&bm[(size_t)r*128 + (cc>>5)], 1u << (cc & 31));
    }
}

// ---------------- per-node aggregation + dense-softmax + relu (bf16 out) ----------------
// M=0 shift (softmax shift-invariant; scores |e| ~ 0.5, exp safe):
//   w_m = exp(e_m) - 1 ;  Z = sum_edges w + N ;  hp = (sum w*hh[m] + S) / Z
// Weight pass: wave h owns head h (strided edges). Accumulate pass: edges are
// split ACROSS waves (i ≡ wave mod 4); each lane o carries 4 channels (uint2 =
// 8B/lane -> one 512B fully-coalesced gather covers all 256 channels). Per-wave
// partial accs combined via LDS (fixed wave order 0..3 -> deterministic).
__global__ __launch_bounds__(256) void aggregate_kernel(
    const unsigned* __restrict__ bm,
    const float* __restrict__ ssrc, const float* __restrict__ sdst,
    const unsigned short* __restrict__ hh,
    const unsigned long long* __restrict__ Sint,
    unsigned short* __restrict__ hout)
{
    __shared__ int   csr_lds[DEGCAP];
    __shared__ float w_lds[4*DEGCAP];
    __shared__ float accs[4][256];
    __shared__ float zp_sh[4];
    const int n = blockIdx.x;
    const int tid = threadIdx.x;
    const int wv = tid >> 6, o = tid & 63;     // o == lane
    const unsigned* brow = bm + (size_t)n*128;
    const float Sv = (float)(long long)Sint[tid] * (1.0f / S_SCALE);

    // per-wave redundant list build (identical values; in-wave LDS ordering)
    unsigned wA = brow[2*o], wB = brow[2*o + 1];
    int cpc = __popc(wA) + __popc(wB);
    int pre = cpc;
    #pragma unroll
    for (int off = 1; off < 64; off <<= 1) {
        int v = __shfl_up(pre, off);
        if (o >= off) pre += v;
    }
    int excl = pre - cpc;
    int cnt = __shfl(pre, 63);                 // block-uniform
    if (cnt <= DEGCAP) {
        int pos = excl, base = o*64;
        unsigned w = wA;
        while (w) { int b = __builtin_ctz(w); csr_lds[pos++] = base + b; w &= w-1; }
        w = wB; base += 32;
        while (w) { int b = __builtin_ctz(w); csr_lds[pos++] = base + b; w &= w-1; }
    }

    if (cnt <= DEGCAP) {                       // block-uniform branch: barriers safe
        // ---- weight pass: wave wv = head wv, edges strided over lanes ----
        float ss = ssrc[n*4 + wv];
        float zp = 0.f;
        for (int i = o; i < cnt; i += 64) {
            int m = csr_lds[i];
            float e = ss + sdst[m*4 + wv];
            e = (e >= 0.f) ? e : 0.2f*e;
            float w = expf(e) - 1.0f;
            w_lds[wv*DEGCAP + i] = w;
            zp += w;
        }
        #pragma unroll
        for (int off = 32; off; off >>= 1) zp += __shfl_xor(zp, off);
        if (o == 0) zp_sh[wv] = zp;
        __syncthreads();                       // publish w_lds + zp_sh

        // ---- accumulate: edges i ≡ wv (mod 4); lane o -> channels 4o..4o+3 ----
        const int h = o >> 4;                  // head of this lane's channels
        const int wbase = h*DEGCAP;
        float a0 = 0.f, a1 = 0.f, a2 = 0.f, a3 = 0.f;
        const unsigned short* hrow0 = hh + (size_t)o*4;
        int i = wv;
        for (; i + 12 < cnt; i += 16) {        // 4 x 512B gathers in flight
            int m0 = csr_lds[i],    m1 = csr_lds[i+4];
            int m2 = csr_lds[i+8],  m3 = csr_lds[i+12];
            float w0 = w_lds[wbase+i],   w1 = w_lds[wbase+i+4];
            float w2 = w_lds[wbase+i+8], w3 = w_lds[wbase+i+12];
            uint2 p0 = *(const uint2*)(hrow0 + (size_t)m0*256);
            uint2 p1 = *(const uint2*)(hrow0 + (size_t)m1*256);
            uint2 p2 = *(const uint2*)(hrow0 + (size_t)m2*256);
            uint2 p3 = *(const uint2*)(hrow0 + (size_t)m3*256);
            a0 += w0*bf2f((unsigned short)(p0.x&0xffffu)); a1 += w0*bf2f((unsigned short)(p0.x>>16));
            a2 += w0*bf2f((unsigned short)(p0.y&0xffffu)); a3 += w0*bf2f((unsigned short)(p0.y>>16));
            a0 += w1*bf2f((unsigned short)(p1.x&0xffffu)); a1 += w1*bf2f((unsigned short)(p1.x>>16));
            a2 += w1*bf2f((unsigned short)(p1.y&0xffffu)); a3 += w1*bf2f((unsigned short)(p1.y>>16));
            a0 += w2*bf2f((unsigned short)(p2.x&0xffffu)); a1 += w2*bf2f((unsigned short)(p2.x>>16));
            a2 += w2*bf2f((unsigned short)(p2.y&0xffffu)); a3 += w2*bf2f((unsigned short)(p2.y>>16));
            a0 += w3*bf2f((unsigned short)(p3.x&0xffffu)); a1 += w3*bf2f((unsigned short)(p3.x>>16));
            a2 += w3*bf2f((unsigned short)(p3.y&0xffffu)); a3 += w3*bf2f((unsigned short)(p3.y>>16));
        }
        for (; i < cnt; i += 4) {
            int m = csr_lds[i];
            float w = w_lds[wbase+i];
            uint2 p = *(const uint2*)(hrow0 + (size_t)m*256);
            a0 += w*bf2f((unsigned short)(p.x&0xffffu)); a1 += w*bf2f((unsigned short)(p.x>>16));
            a2 += w*bf2f((unsigned short)(p.y&0xffffu)); a3 += w*bf2f((unsigned short)(p.y>>16));
        }
        float4 av; av.x = a0; av.y = a1; av.z = a2; av.w = a3;
        *(float4*)&accs[wv][o*4] = av;
        __syncthreads();                       // publish accs

        // ---- combine: thread tid owns channel tid (deterministic wv order) ----
        float sum4 = accs[0][tid] + accs[1][tid] + accs[2][tid] + accs[3][tid];
        float Z = zp_sh[tid >> 6] + (float)NNODES;
        float hp = (sum4 + Sv) / Z;
        hout[(size_t)n*256 + tid] = f2bf(fmaxf(hp, 0.f));
    } else {
        // overflow fallback (never expected, Poisson(32) rows): direct scan, M=0
        float ss = ssrc[n*4 + wv];
        float zp = 0.f, acc = 0.f;
        for (int m = 0; m < NNODES; ++m) {
            if ((brow[m>>5] >> (m & 31)) & 1u) {
                float e = ss + sdst[m*4 + wv];
                e = (e >= 0.f) ? e : 0.2f*e;
                float w = expf(e) - 1.0f;
                zp += w;
                acc += w * bf2f(hh[(size_t)m*256 + wv*64 + o]);
            }
        }
        float Z  = zp + (float)NNODES;
        float hp = (acc + Sv) / Z;
        hout[(size_t)n*256 + wv*64 + o] = f2bf(fmaxf(hp, 0.f));
    }
}

// ---------------- host: size-based input resolution ----------------
static int find_size(const int* sz, int n, int want, int fallback)
{
    for (int i = 0; i < n; ++i) if (sz[i] == want) return i;
    return fallback;
}

extern "C" void kernel_launch(void* const* d_in, const int* in_sizes, int n_in,
                              void* d_out, int out_size, void* d_ws, size_t ws_size,
                              hipStream_t stream)
{
    int ix   = find_size(in_sizes, n_in, NNODES*D_IN, 0);
    int ie   = find_size(in_sizes, n_in, 2*NEDGES, 1);
    int iwin = find_size(in_sizes, n_in, D_IN*D_H, 2);
    int ibin = find_size(in_sizes, n_in, D_H, 3);
    int iwg  = find_size(in_sizes, n_in, 2*NHEAD*D_H*D_HEAD, 4);
    int ia   = find_size(in_sizes, n_in, 2*NHEAD*2*D_HEAD, 5);
    int iwo  = find_size(in_sizes, n_in, D_H*D_OUT, 6);
    int ibo  = find_size(in_sizes, n_in, D_OUT, 7);

    const float* x    = (const float*)d_in[ix];
    const int*   ei   = (const int*)d_in[ie];
    const float* Win  = (const float*)d_in[iwin];
    const float* bin_ = (const float*)d_in[ibin];
    const float* Wg   = (const float*)d_in[iwg];
    const float* a    = (const float*)d_in[ia];
    const float* Wout = (const float*)d_in[iwo];
    const float* bout = (const float*)d_in[ibo];
    float* out = (float*)d_out;

    char* ws = (char*)d_ws;
    unsigned short*     xb    = (unsigned short*)(ws + OFF_XB);
    unsigned short*     h0    = (unsigned short*)(ws + OFF_H0);
    unsigned short*     h1    = (unsigned short*)(ws + OFF_H1);
    unsigned short*     hh    = (unsigned short*)(ws + OFF_HH);
    unsigned long long* Sint  = (unsigned long long*)(ws + OFF_SINT);
    float*              ssrc  = (float*)(ws + OFF_SSRC);
    float*              sdst  = (float*)(ws + OFF_SDST);
    unsigned short*     WinT  = (unsigned short*)(ws + OFF_WINT);
    unsigned short*     WgT   = (unsigned short*)(ws + OFF_WGT);
    unsigned short*     WoutT = (unsigned short*)(ws + OFF_WOUTT);
    unsigned*           bm    = (unsigned*)(ws + OFF_BM);

    // d1: zero bitmap + Sint + weight convert + x->bf16 (disjoint memory)
    k_init<<<512, 256, 0, stream>>>(Win, Wg, Wout, x, WinT, WgT, WoutT, xb,
                                    (uint4*)bm, Sint);

    // d2: h0 = relu(xb @ Win + bin) (bf16 out, XCD-swizzled) + edge bitmap tail
    gemm_mfma<<<512, 256, 0, stream>>>(xb, WinT, bin_, nullptr, h0,
                                       D_H, D_IN, 1,
                                       nullptr, nullptr, nullptr, nullptr,
                                       ei, bm);

    unsigned short* hin = h0;
    unsigned short* hcur = h1;
    for (int l = 0; l < 2; ++l) {
        // d3/d5: hh = hin @ Wg[l] (bf16 out, + scores + fixed-point S atomics)
        dim3 g2(D_H/64, NNODES/32);
        gemm_mfma<<<g2, 256, 0, stream>>>(hin, WgT + (size_t)l*NHEAD*D_HEAD*D_H,
                                          nullptr, nullptr, hh,
                                          D_H, D_H, 0,
                                          a + (size_t)l*NHEAD*128, ssrc, sdst,
                                          Sint + (size_t)l*256,
                                          nullptr, nullptr);
        // d4/d6: aggregate (bf16 out, 4096x1, vectorized 512B gathers)
        aggregate_kernel<<<NNODES, 256, 0, stream>>>(bm, ssrc, sdst, hh,
                                                     Sint + (size_t)l*256, hcur);
        unsigned short* t = hin; hin = hcur; hcur = t;
    }

    // d7: out = hin @ Wout + bout  (f32 out)
    {
        dim3 g(D_OUT/64, NNODES/32);
        gemm_mfma<<<g, 256, 0, stream>>>(hin, WoutT, bout, out, nullptr,
                                         D_OUT, D_H, 0,
                                         nullptr, nullptr, nullptr, nullptr,
                                         nullptr, nullptr);
    }
}

// Round 20
// 71.920 us; speedup vs baseline: 1.2127x; 1.0023x over previous
//
#include <hip/hip_runtime.h>
#include <hip/hip_bf16.h>

#define NNODES 4096
#define NEDGES 131072
#define D_IN   768
#define D_H    256
#define NHEAD  4
#define D_HEAD 64
#define D_OUT  128
#define DEGCAP 192
#define S_SCALE 1048576.0f          // 2^20 fixed-point for deterministic S atomics

typedef __attribute__((ext_vector_type(4))) float f32x4;
typedef __attribute__((ext_vector_type(8))) short bf16x8;
typedef __attribute__((ext_vector_type(8))) unsigned short u16x8;

static __device__ __forceinline__ unsigned short f2bf(float f) {
    __hip_bfloat16 h = __float2bfloat16(f);
    return *reinterpret_cast<unsigned short*>(&h);
}
static __device__ __forceinline__ float bf2f(unsigned short u) {
    return __uint_as_float((unsigned)u << 16);
}

// ---------------- workspace layout (bytes) ----------------
#define OFF_XB     (0u)                          // 4096*768*2 = 6MB (x as bf16)
#define OFF_H0     (6u<<20)                      // 2MB bf16
#define OFF_H1     (8u<<20)                      // 2MB bf16
#define OFF_HH     (10u<<20)                     // 2MB bf16
#define OFF_SINT   (12u<<20)                     // 2 layers * 256 * 8B = 4096
#define OFF_SSRC   (OFF_SINT + 4096u)            // 65536
#define OFF_SDST   (OFF_SSRC + 65536u)           // 65536
#define OFF_WINT   (OFF_SDST + 65536u)           // 393216
#define OFF_WGT    (OFF_WINT + 393216u)          // 262144
#define OFF_WOUTT  (OFF_WGT + 262144u)           // 65536
#define OFF_BM     (OFF_WOUTT + 65536u)          // 2MB

// ---------------- init: zero bitmap + Sint + weight convert + x -> bf16 ----------------
__global__ __launch_bounds__(256) void k_init(
    const float* __restrict__ Win, const float* __restrict__ Wg,
    const float* __restrict__ Wout, const float* __restrict__ x,
    unsigned short* __restrict__ WinT, unsigned short* __restrict__ WgT,
    unsigned short* __restrict__ WoutT, unsigned short* __restrict__ xb,
    uint4* __restrict__ bm4, unsigned long long* __restrict__ Sint)
{
    __shared__ float tile[32][33];
    const int tid = threadIdx.x, bid = blockIdx.x;
    bm4[bid*256 + tid] = make_uint4(0u,0u,0u,0u);
    if (bid == 0) { Sint[tid] = 0ull; Sint[256 + tid] = 0ull; }

    // x -> bf16 (identical rounding to in-staging convert)
    {
        const float4* x4 = (const float4*)x;
        ushort4* xb4 = (ushort4*)xb;
        for (int i = bid*256 + tid; i < (NNODES*D_IN)/4; i += 512*256) {
            float4 v = x4[i];
            ushort4 o;
            o.x = f2bf(v.x); o.y = f2bf(v.y); o.z = f2bf(v.z); o.w = f2bf(v.w);
            xb4[i] = o;
        }
    }

    if (bid < 352) {
        const float* src; unsigned short* dst; int R, Cc, tr, tc;
        if (bid < 192)      { src = Win;  dst = WinT;  R = 768; Cc = 256; tr = bid >> 3; tc = bid & 7; }
        else if (bid < 320) { int t = bid - 192; int m = t >> 4, s = t & 15;
                              src = Wg + (size_t)m*16384; dst = WgT + (size_t)m*16384;
                              R = 256; Cc = 64; tr = s >> 1; tc = s & 1; }
        else                { int t = bid - 320; src = Wout; dst = WoutT;
                              R = 256; Cc = 128; tr = t >> 2; tc = t & 3; }
        int ci = tid & 31, rq = tid >> 5;
        #pragma unroll
        for (int rr = rq; rr < 32; rr += 8)
            tile[rr][ci] = src[(size_t)(tr*32+rr)*Cc + tc*32 + ci];
        __syncthreads();
        int ri = tid & 31, cq = tid >> 5;
        #pragma unroll
        for (int cc = cq; cc < 32; cc += 8)
            dst[(size_t)(tc*32+cc)*R + tr*32 + ri] = f2bf(tile[ri][cc]);
    }
}

// ---------------- MFMA GEMM: C = act(A@B + bias), A/B both bf16 ----------------
// A: MxK bf16 row-major. BT: NxK bf16 (pre-transposed). 32x64 tile, BK=64,
// 256 thr = 4 waves (wave = 16-col strip), 4 MFMA/wave/iter.
// ei != null (h0): 1D grid of 512, XCD-swizzled bx/by + edge-bitmap tail.
// a_l != null (hh): epilogue computes ssrc/sdst + fixed-point Sint col sums.
__global__ __launch_bounds__(256) void gemm_mfma(
    const unsigned short* __restrict__ A, const unsigned short* __restrict__ BT,
    const float* __restrict__ bias, float* __restrict__ Cf,
    unsigned short* __restrict__ Cb,
    int N, int K, int relu,
    const float* __restrict__ a_l, float* __restrict__ ssrc,
    float* __restrict__ sdst, unsigned long long* __restrict__ Sint,
    const int* __restrict__ ei, unsigned* __restrict__ bm)
{
    __shared__ unsigned short As[32][72];   // [row][k] bf16, 144B stride (2-way banks: free)
    __shared__ unsigned short Bs[64][72];   // [col][k] bf16
    __shared__ float sredS[4][32], sredD[4][32];
    const int tid = threadIdx.x;
    int bx, by;
    if (ei) {   // h0: 1D grid 512, nbx=4, XCD-aware remap (bijective)
        int bid = blockIdx.x;
        int xcd = bid & 7, q = bid >> 3;
        bx = q & 3;
        by = (q >> 2)*8 + xcd;
    } else {
        bx = blockIdx.x; by = blockIdx.y;
    }
    const int wc = tid >> 6;                 // wave id = column strip
    const int lane = tid & 63;
    const int g = lane >> 4, c = lane & 15;
    const int ar = tid >> 3, ak = (tid & 7) * 8;   // A stage: 32r x (8thr x 8 u16)
    const int bc = tid >> 2, bk = (tid & 3) * 16;  // B stage: 64c x (4thr x 16 u16)
    f32x4 acc0 = {0.f,0.f,0.f,0.f}, acc1 = {0.f,0.f,0.f,0.f};
    const unsigned short* Arow = A + (size_t)(by*32 + ar)*K;
    const unsigned short* Brow = BT + (size_t)(bx*64 + bc)*K;

    for (int k0 = 0; k0 < K; k0 += 64) {
        u16x8 avv = *(const u16x8*)&Arow[k0 + ak];
        u16x8 bv0 = *(const u16x8*)&Brow[k0 + bk];
        u16x8 bv1 = *(const u16x8*)&Brow[k0 + bk + 8];
        *(u16x8*)&As[ar][ak]     = avv;
        *(u16x8*)&Bs[bc][bk]     = bv0;
        *(u16x8*)&Bs[bc][bk + 8] = bv1;
        __syncthreads();
        bf16x8 b0  = *(bf16x8*)&Bs[wc*16 + c][g*8];
        bf16x8 b1  = *(bf16x8*)&Bs[wc*16 + c][32 + g*8];
        bf16x8 a00 = *(bf16x8*)&As[c][g*8];
        bf16x8 a01 = *(bf16x8*)&As[c][32 + g*8];
        bf16x8 a10 = *(bf16x8*)&As[16 + c][g*8];
        bf16x8 a11 = *(bf16x8*)&As[16 + c][32 + g*8];
        acc0 = __builtin_amdgcn_mfma_f32_16x16x32_bf16(a00, b0, acc0, 0, 0, 0);
        acc0 = __builtin_amdgcn_mfma_f32_16x16x32_bf16(a01, b1, acc0, 0, 0, 0);
        acc1 = __builtin_amdgcn_mfma_f32_16x16x32_bf16(a10, b0, acc1, 0, 0, 0);
        acc1 = __builtin_amdgcn_mfma_f32_16x16x32_bf16(a11, b1, acc1, 0, 0, 0);
        __syncthreads();
    }

    const int col = bx*64 + wc*16 + c;
    float bb = bias ? bias[col] : 0.f;
    #pragma unroll
    for (int t = 0; t < 2; ++t) {
        f32x4 av = t ? acc1 : acc0;
        #pragma unroll
        for (int i = 0; i < 4; ++i) {
            int r = by*32 + t*16 + g*4 + i;
            float v = av[i] + bb;
            if (relu) v = fmaxf(v, 0.f);
            if (Cb) Cb[(size_t)r*N + col] = f2bf(v);
            else    Cf[(size_t)r*N + col] = v;
        }
    }

    if (a_l) {
        int h = bx;
        float as = a_l[h*128 + wc*16 + c];
        float ad = a_l[h*128 + 64 + wc*16 + c];
        float ps[8], pd[8], cs = 0.f;
        #pragma unroll
        for (int t = 0; t < 2; ++t) {
            f32x4 av = t ? acc1 : acc0;
            #pragma unroll
            for (int i = 0; i < 4; ++i) {
                ps[t*4+i] = av[i] * as;
                pd[t*4+i] = av[i] * ad;
                cs += av[i];
            }
        }
        #pragma unroll
        for (int off = 1; off < 16; off <<= 1) {
            #pragma unroll
            for (int j = 0; j < 8; ++j) {
                ps[j] += __shfl_xor(ps[j], off);
                pd[j] += __shfl_xor(pd[j], off);
            }
        }
        if (c == 0) {
            #pragma unroll
            for (int t = 0; t < 2; ++t)
                #pragma unroll
                for (int i = 0; i < 4; ++i) {
                    sredS[wc][t*16 + g*4 + i] = ps[t*4+i];
                    sredD[wc][t*16 + g*4 + i] = pd[t*4+i];
                }
        }
        // 32-row column sum -> deterministic fixed-point atomic
        cs += __shfl_xor(cs, 16);
        cs += __shfl_xor(cs, 32);
        if (g == 0) {
            long long q = (long long)llrintf(cs * S_SCALE);
            atomicAdd(&Sint[col], (unsigned long long)q);   // 2's-complement add
        }
        __syncthreads();
        if (tid < 32) {
            float s1 = sredS[0][tid] + sredS[1][tid] + sredS[2][tid] + sredS[3][tid];
            float s2 = sredD[0][tid] + sredD[1][tid] + sredD[2][tid] + sredD[3][tid];
            int r = by*32 + tid;
            ssrc[r*4 + h] = s1;
            sdst[r*4 + h] = s2;
        }
    }

    if (ei) {
        // adjacency bitmap build: 512 blocks x 256 threads == NEDGES (flat bid)
        __shared__ int flag;
        int bid = blockIdx.x;
        if (tid < 64) {
            int v = ei[2*tid + 1];
            unsigned long long ball = __ballot(v == 0);
            if (tid == 0) flag = (ball == ~0ull) ? 1 : 0;
        }
        __syncthreads();
        int is64 = flag;
        int k = bid*256 + tid;
        int r  = is64 ? ei[2*k]            : ei[k];
        int cc = is64 ? ei[2*NEDGES + 2*k] : ei[NEDGES + k];
        r &= (NNODES-1); cc &= (NNODES-1);
        atomicOr(&bm[(size_t)r*128 + (cc>>5)], 1u << (cc & 31));
    }
}

// ---------------- per-node aggregation + dense-softmax + relu (bf16 out) ----------------
// M=0 shift (softmax shift-invariant; scores |e| ~ 0.5, exp safe):
//   w_m = exp(e_m) - 1 ;  Z = sum_edges w + N ;  hp = (sum w*hh[m] + S) / Z
// Weight pass: wave h owns head h (strided edges; 4B gathers share cache lines
// across heads). Accumulate pass: 2 edges per 1KB gather -- lanes 0-31 take
// edge i ≡ wv (mod 8), lanes 32-63 edge i ≡ wv+4 (mod 8); lane q covers
// channels 8q..8q+7 (uint4 = 16B/lane). 8 deterministic partials combined in
// fixed order via LDS.
__global__ __launch_bounds__(256) void aggregate_kernel(
    const unsigned* __restrict__ bm,
    const float* __restrict__ ssrc, const float* __restrict__ sdst,
    const unsigned short* __restrict__ hh,
    const unsigned long long* __restrict__ Sint,
    unsigned short* __restrict__ hout)
{
    __shared__ int   csr_lds[DEGCAP];
    __shared__ float w_lds[4*DEGCAP];
    __shared__ float accs[8][256];
    __shared__ float zp_sh[4];
    const int n = blockIdx.x;
    const int tid = threadIdx.x;
    const int wv = tid >> 6, o = tid & 63;     // o == lane
    const unsigned* brow = bm + (size_t)n*128;
    const float Sv = (float)(long long)Sint[tid] * (1.0f / S_SCALE);

    // per-wave redundant list build (identical values; in-wave LDS ordering)
    unsigned wA = brow[2*o], wB = brow[2*o + 1];
    int cpc = __popc(wA) + __popc(wB);
    int pre = cpc;
    #pragma unroll
    for (int off = 1; off < 64; off <<= 1) {
        int v = __shfl_up(pre, off);
        if (o >= off) pre += v;
    }
    int excl = pre - cpc;
    int cnt = __shfl(pre, 63);                 // block-uniform
    if (cnt <= DEGCAP) {
        int pos = excl, base = o*64;
        unsigned w = wA;
        while (w) { int b = __builtin_ctz(w); csr_lds[pos++] = base + b; w &= w-1; }
        w = wB; base += 32;
        while (w) { int b = __builtin_ctz(w); csr_lds[pos++] = base + b; w &= w-1; }
    }

    if (cnt <= DEGCAP) {                       // block-uniform branch: barriers safe
        // ---- weight pass: wave wv = head wv, edges strided over lanes ----
        float ss = ssrc[n*4 + wv];
        float zp = 0.f;
        for (int i = o; i < cnt; i += 64) {
            int m = csr_lds[i];
            float e = ss + sdst[m*4 + wv];
            e = (e >= 0.f) ? e : 0.2f*e;
            float w = expf(e) - 1.0f;
            w_lds[wv*DEGCAP + i] = w;
            zp += w;
        }
        #pragma unroll
        for (int off = 32; off; off >>= 1) zp += __shfl_xor(zp, off);
        if (o == 0) zp_sh[wv] = zp;
        __syncthreads();                       // publish w_lds + zp_sh

        // ---- accumulate: 2 edges per 1KB gather; lane q -> channels 8q..8q+7 ----
        const int s = o >> 5, q = o & 31;
        const int hq = q >> 3;                 // head of this lane's channels
        const int wbase = hq*DEGCAP;
        float a0=0.f,a1=0.f,a2=0.f,a3=0.f,a4=0.f,a5=0.f,a6=0.f,a7=0.f;
        const unsigned short* hrow0 = hh + (size_t)q*8;
        int i = wv + s*4;                      // edges i ≡ wv+4s (mod 8)
        for (; i + 8 < cnt; i += 16) {         // 2 gathers in flight
            int m0 = csr_lds[i], m1 = csr_lds[i+8];
            float w0 = w_lds[wbase+i], w1 = w_lds[wbase+i+8];
            uint4 p0 = *(const uint4*)(hrow0 + (size_t)m0*256);
            uint4 p1 = *(const uint4*)(hrow0 + (size_t)m1*256);
            a0 += w0*bf2f((unsigned short)(p0.x&0xffffu)); a1 += w0*bf2f((unsigned short)(p0.x>>16));
            a2 += w0*bf2f((unsigned short)(p0.y&0xffffu)); a3 += w0*bf2f((unsigned short)(p0.y>>16));
            a4 += w0*bf2f((unsigned short)(p0.z&0xffffu)); a5 += w0*bf2f((unsigned short)(p0.z>>16));
            a6 += w0*bf2f((unsigned short)(p0.w&0xffffu)); a7 += w0*bf2f((unsigned short)(p0.w>>16));
            a0 += w1*bf2f((unsigned short)(p1.x&0xffffu)); a1 += w1*bf2f((unsigned short)(p1.x>>16));
            a2 += w1*bf2f((unsigned short)(p1.y&0xffffu)); a3 += w1*bf2f((unsigned short)(p1.y>>16));
            a4 += w1*bf2f((unsigned short)(p1.z&0xffffu)); a5 += w1*bf2f((unsigned short)(p1.z>>16));
            a6 += w1*bf2f((unsigned short)(p1.w&0xffffu)); a7 += w1*bf2f((unsigned short)(p1.w>>16));
        }
        for (; i < cnt; i += 8) {
            int m = csr_lds[i];
            float w = w_lds[wbase+i];
            uint4 p = *(const uint4*)(hrow0 + (size_t)m*256);
            a0 += w*bf2f((unsigned short)(p.x&0xffffu)); a1 += w*bf2f((unsigned short)(p.x>>16));
            a2 += w*bf2f((unsigned short)(p.y&0xffffu)); a3 += w*bf2f((unsigned short)(p.y>>16));
            a4 += w*bf2f((unsigned short)(p.z&0xffffu)); a5 += w*bf2f((unsigned short)(p.z>>16));
            a6 += w*bf2f((unsigned short)(p.w&0xffffu)); a7 += w*bf2f((unsigned short)(p.w>>16));
        }
        float4 lo; lo.x=a0; lo.y=a1; lo.z=a2; lo.w=a3;
        float4 hi; hi.x=a4; hi.y=a5; hi.z=a6; hi.w=a7;
        *(float4*)&accs[wv*2+s][q*8]     = lo;
        *(float4*)&accs[wv*2+s][q*8 + 4] = hi;
        __syncthreads();                       // publish accs

        // ---- combine: thread tid owns channel tid (fixed partial order 0..7) ----
        float sum8 = accs[0][tid] + accs[1][tid] + accs[2][tid] + accs[3][tid]
                   + accs[4][tid] + accs[5][tid] + accs[6][tid] + accs[7][tid];
        float Z = zp_sh[tid >> 6] + (float)NNODES;
        float hp = (sum8 + Sv) / Z;
        hout[(size_t)n*256 + tid] = f2bf(fmaxf(hp, 0.f));
    } else {
        // overflow fallback (never expected, Poisson(32) rows): direct scan, M=0
        float ss = ssrc[n*4 + wv];
        float zp = 0.f, acc = 0.f;
        for (int m = 0; m < NNODES; ++m) {
            if ((brow[m>>5] >> (m & 31)) & 1u) {
                float e = ss + sdst[m*4 + wv];
                e = (e >= 0.f) ? e : 0.2f*e;
                float w = expf(e) - 1.0f;
                zp += w;
                acc += w * bf2f(hh[(size_t)m*256 + wv*64 + o]);
            }
        }
        float Z  = zp + (float)NNODES;
        float hp = (acc + Sv) / Z;
        hout[(size_t)n*256 + wv*64 + o] = f2bf(fmaxf(hp, 0.f));
    }
}

// ---------------- host: size-based input resolution ----------------
static int find_size(const int* sz, int n, int want, int fallback)
{
    for (int i = 0; i < n; ++i) if (sz[i] == want) return i;
    return fallback;
}

extern "C" void kernel_launch(void* const* d_in, const int* in_sizes, int n_in,
                              void* d_out, int out_size, void* d_ws, size_t ws_size,
                              hipStream_t stream)
{
    int ix   = find_size(in_sizes, n_in, NNODES*D_IN, 0);
    int ie   = find_size(in_sizes, n_in, 2*NEDGES, 1);
    int iwin = find_size(in_sizes, n_in, D_IN*D_H, 2);
    int ibin = find_size(in_sizes, n_in, D_H, 3);
    int iwg  = find_size(in_sizes, n_in, 2*NHEAD*D_H*D_HEAD, 4);
    int ia   = find_size(in_sizes, n_in, 2*NHEAD*2*D_HEAD, 5);
    int iwo  = find_size(in_sizes, n_in, D_H*D_OUT, 6);
    int ibo  = find_size(in_sizes, n_in, D_OUT, 7);

    const float* x    = (const float*)d_in[ix];
    const int*   ei   = (const int*)d_in[ie];
    const float* Win  = (const float*)d_in[iwin];
    const float* bin_ = (const float*)d_in[ibin];
    const float* Wg   = (const float*)d_in[iwg];
    const float* a    = (const float*)d_in[ia];
    const float* Wout = (const float*)d_in[iwo];
    const float* bout = (const float*)d_in[ibo];
    float* out = (float*)d_out;

    char* ws = (char*)d_ws;
    unsigned short*     xb    = (unsigned short*)(ws + OFF_XB);
    unsigned short*     h0    = (unsigned short*)(ws + OFF_H0);
    unsigned short*     h1    = (unsigned short*)(ws + OFF_H1);
    unsigned short*     hh    = (unsigned short*)(ws + OFF_HH);
    unsigned long long* Sint  = (unsigned long long*)(ws + OFF_SINT);
    float*              ssrc  = (float*)(ws + OFF_SSRC);
    float*              sdst  = (float*)(ws + OFF_SDST);
    unsigned short*     WinT  = (unsigned short*)(ws + OFF_WINT);
    unsigned short*     WgT   = (unsigned short*)(ws + OFF_WGT);
    unsigned short*     WoutT = (unsigned short*)(ws + OFF_WOUTT);
    unsigned*           bm    = (unsigned*)(ws + OFF_BM);

    // d1: zero bitmap + Sint + weight convert + x->bf16 (disjoint memory)
    k_init<<<512, 256, 0, stream>>>(Win, Wg, Wout, x, WinT, WgT, WoutT, xb,
                                    (uint4*)bm, Sint);

    // d2: h0 = relu(xb @ Win + bin) (bf16 out, XCD-swizzled) + edge bitmap tail
    gemm_mfma<<<512, 256, 0, stream>>>(xb, WinT, bin_, nullptr, h0,
                                       D_H, D_IN, 1,
                                       nullptr, nullptr, nullptr, nullptr,
                                       ei, bm);

    unsigned short* hin = h0;
    unsigned short* hcur = h1;
    for (int l = 0; l < 2; ++l) {
        // d3/d5: hh = hin @ Wg[l] (bf16 out, + scores + fixed-point S atomics)
        dim3 g2(D_H/64, NNODES/32);
        gemm_mfma<<<g2, 256, 0, stream>>>(hin, WgT + (size_t)l*NHEAD*D_HEAD*D_H,
                                          nullptr, nullptr, hh,
                                          D_H, D_H, 0,
                                          a + (size_t)l*NHEAD*128, ssrc, sdst,
                                          Sint + (size_t)l*256,
                                          nullptr, nullptr);
        // d4/d6: aggregate (bf16 out, 4096x1, 1KB dual-edge gathers)
        aggregate_kernel<<<NNODES, 256, 0, stream>>>(bm, ssrc, sdst, hh,
                                                     Sint + (size_t)l*256, hcur);
        unsigned short* t = hin; hin = hcur; hcur = t;
    }

    // d7: out = hin @ Wout + bout  (f32 out)
    {
        dim3 g(D_OUT/64, NNODES/32);
        gemm_mfma<<<g, 256, 0, stream>>>(hin, WoutT, bout, out, nullptr,
                                         D_OUT, D_H, 0,
                                         nullptr, nullptr, nullptr, nullptr,
                                         nullptr, nullptr);
    }
}